// Round 2
// baseline (787.335 us; speedup 1.0000x reference)
//
#include <hip/hip_runtime.h>

// GameURMAttention: x[65536,512] -> QKV -> 8-head SDPA (S=16,D=64) -> out-proj.
// R2: single fused kernel. k0 converts x/w_qkv/w_o to bf16 in ws (tiered fallback).
//  - phase 1: QKV GEMM, 2 heads/pass (4 passes), X staged bf16->LDS, W loaded
//    DIRECTLY global->frag (no LDS: each W col used by exactly one wave).
//  - phase 2: per-batch-per-wave attention (round-1-proven path), attn kept in
//    registers (packed bf16, 8 heads x 4 frags = 64 VGPRs).
//  - phase 3: out-proj: attn_h staged regs->LDS per head (=K-chunk), w_o direct
//    global->frag, acc over all 8 heads, store fp32 out. No separate oproj kernel.

#define HID   512
#define NH4   4          // head-pairs

typedef __attribute__((ext_vector_type(4))) float  float4v;
typedef __attribute__((ext_vector_type(8))) short  short8;
typedef __attribute__((ext_vector_type(4))) short  short4v;
typedef __attribute__((ext_vector_type(8))) __bf16 bf16x8;

static __device__ __forceinline__ short bf16rne(float f) {
    union { float f; unsigned u; } v; v.f = f;
    unsigned u = v.u + 0x7FFFu + ((v.u >> 16) & 1u);
    return (short)(u >> 16);
}

static __device__ __forceinline__ short8 pack8(float4v a, float4v b) {
    short8 o;
    o[0] = bf16rne(a[0]); o[1] = bf16rne(a[1]); o[2] = bf16rne(a[2]); o[3] = bf16rne(a[3]);
    o[4] = bf16rne(b[0]); o[5] = bf16rne(b[1]); o[6] = bf16rne(b[2]); o[7] = bf16rne(b[3]);
    return o;
}

static __device__ __forceinline__ void cvt8_store(short* dst, const float* src) {
    float4v a = *(const float4v*)src;
    float4v b = *(const float4v*)(src + 4);
    *(short8*)dst = pack8(a, b);
}

static __device__ __forceinline__ float4v mfma16(short8 a, short8 b, float4v c) {
    union { short8 s; bf16x8 v; } ua, ub;
    ua.s = a; ub.s = b;
    return __builtin_amdgcn_mfma_f32_16x16x32_bf16(ua.v, ub.v, c, 0, 0, 0);
}

// ---------------- k0: fp32 -> bf16 conversion ----------------
__global__ void cvt_kernel(const float* __restrict__ src, short* __restrict__ dst, int n4) {
    int i = blockIdx.x * 256 + threadIdx.x;
    if (i >= n4) return;
    float4v v = *(const float4v*)(src + (size_t)i * 4);
    short4v o;
    o[0] = bf16rne(v[0]); o[1] = bf16rne(v[1]); o[2] = bf16rne(v[2]); o[3] = bf16rne(v[3]);
    *(short4v*)(dst + (size_t)i * 4) = o;
}

// ---------------- fused kernel ----------------
// 1024 blocks x 256 threads (4 waves). M-tile = 64 rows = 4 batches.
// LDS: Lx 64x72 bf16 (X chunk / attn_h chunk, 9216 B)
//      Ls 2 heads x {Q 64x72, K 64x72, VT 64x88, P 4x16x40} = 69632 B
// Scratch offsets per head j (shorts): Q=j*17408, K=+4608, VT=+9216, P=+14848.
__global__ __launch_bounds__(256, 2)
void fused_kernel(const float* __restrict__ x,   const short* __restrict__ xb,
                  const float* __restrict__ wqf, const short* __restrict__ wqb,
                  const float* __restrict__ wof, const short* __restrict__ wob,
                  const int tier, float* __restrict__ out) {
    __shared__ __align__(16) short Lx[64 * 72];
    __shared__ __align__(16) short Ls[2 * 17408];

    const int tid  = threadIdx.x;
    const int wave = tid >> 6;
    const int lane = tid & 63;
    const int ln   = lane & 15;
    const int q8   = (lane >> 4) * 8;
    const int qrow = (lane >> 4) * 4;
    const int m0   = blockIdx.x * 64;
    const int rb   = wave * 16;          // this wave's batch rows in the tile

    // zero VT + P regions once: data cols are rewritten every pass, pads persist
    {
        short8 z = (short8){0, 0, 0, 0, 0, 0, 0, 0};
        #pragma unroll
        for (int j = 0; j < 2; ++j) {
            for (int i = tid; i < 704; i += 256)           // VT: 64*88 shorts
                *(short8*)&Ls[j * 17408 + 9216 + i * 8] = z;
            for (int i = tid; i < 320; i += 256)           // P: 4*16*40 shorts
                *(short8*)&Ls[j * 17408 + 14848 + i * 8] = z;
        }
    }

    short4v pk[8][4];    // per-wave attn outputs, packed bf16: [head][dc] x 4 rows

    #pragma unroll
    for (int hp = 0; hp < NH4; ++hp) {
        // B-frag row byte-offsets (row index into w_qkv) for this wave's 6 n-cols
        size_t woff[6];
        #pragma unroll
        for (int fc = 0; fc < 6; ++fc) {
            int n = wave * 96 + fc * 16 + ln;
            int j = (n >= 192) ? 1 : 0;
            int t = n - j * 192;
            int grow = (t >> 6) * HID + (hp * 2 + j) * 64 + (t & 63);
            woff[fc] = (size_t)grow * HID;
        }

        float4v acc[4][6];
        #pragma unroll
        for (int fr = 0; fr < 4; ++fr)
            #pragma unroll
            for (int fc = 0; fc < 6; ++fc)
                acc[fr][fc] = (float4v){0.f, 0.f, 0.f, 0.f};

        for (int kb = 0; kb < 8; ++kb) {
            __syncthreads();   // WAR: prior reads of Lx done
            {
                int r0 = tid >> 3, c8 = (tid & 7) * 8;
                if (tier == 2) {
                    *(short8*)&Lx[r0 * 72 + c8] =
                        *(const short8*)&xb[(size_t)(m0 + r0) * HID + kb * 64 + c8];
                    *(short8*)&Lx[(r0 + 32) * 72 + c8] =
                        *(const short8*)&xb[(size_t)(m0 + r0 + 32) * HID + kb * 64 + c8];
                } else {
                    cvt8_store(&Lx[r0 * 72 + c8], &x[(size_t)(m0 + r0) * HID + kb * 64 + c8]);
                    cvt8_store(&Lx[(r0 + 32) * 72 + c8], &x[(size_t)(m0 + r0 + 32) * HID + kb * 64 + c8]);
                }
            }
            __syncthreads();
            #pragma unroll
            for (int ks = 0; ks < 2; ++ks) {
                const int ko = ks * 32 + q8;
                short8 a[4], b[6];
                #pragma unroll
                for (int fr = 0; fr < 4; ++fr)
                    a[fr] = *(const short8*)&Lx[(fr * 16 + ln) * 72 + ko];
                #pragma unroll
                for (int fc = 0; fc < 6; ++fc) {
                    if (tier >= 1) {
                        b[fc] = *(const short8*)&wqb[woff[fc] + kb * 64 + ko];
                    } else {
                        float4v f0 = *(const float4v*)&wqf[woff[fc] + kb * 64 + ko];
                        float4v f1 = *(const float4v*)&wqf[woff[fc] + kb * 64 + ko + 4];
                        b[fc] = pack8(f0, f1);
                    }
                }
                #pragma unroll
                for (int fr = 0; fr < 4; ++fr)
                    #pragma unroll
                    for (int fc = 0; fc < 6; ++fc)
                        acc[fr][fc] = mfma16(a[fr], b[fc], acc[fr][fc]);
            }
        }
        __syncthreads();   // WAR: prior pass's attention reads of Ls done

        // ---- epilogue: C frags -> Ls Q(x0.125)/K/VT per head, bf16 ----
        #pragma unroll
        for (int fr = 0; fr < 4; ++fr) {
            #pragma unroll
            for (int fc = 0; fc < 6; ++fc) {
                const int c  = wave * 96 + fc * 16 + ln;    // wave-uniform region per frag
                const int j  = (c >= 192) ? 1 : 0;
                const int cc = c - j * 192;
                const int B  = j * 17408;
                const int mb = fr * 16 + qrow;
                const float4v v = acc[fr][fc];
                if (cc < 64) {
                    #pragma unroll
                    for (int r = 0; r < 4; ++r)
                        Ls[B + (mb + r) * 72 + cc] = bf16rne(v[r] * 0.125f);
                } else if (cc < 128) {
                    #pragma unroll
                    for (int r = 0; r < 4; ++r)
                        Ls[B + 4608 + (mb + r) * 72 + (cc - 64)] = bf16rne(v[r]);
                } else {
                    #pragma unroll
                    for (int r = 0; r < 4; ++r)
                        Ls[B + 9216 + (cc - 128) * 88 + mb + r] = bf16rne(v[r]);
                }
            }
        }
        __syncthreads();

        // ---- attention: wave w = batch w; heads hp*2, hp*2+1 ----
        #pragma unroll
        for (int j = 0; j < 2; ++j) {
            const int B = j * 17408;
            const short* qp = &Ls[B + (rb + ln) * 72 + q8];
            const short* kp = &Ls[B + 4608 + (rb + ln) * 72 + q8];
            short8 aq0 = *(const short8*)qp;
            short8 aq1 = *(const short8*)(qp + 32);
            short8 bk0 = *(const short8*)kp;
            short8 bk1 = *(const short8*)(kp + 32);
            float4v s = (float4v){0.f, 0.f, 0.f, 0.f};
            s = mfma16(aq0, bk0, s);
            s = mfma16(aq1, bk1, s);      // s[r] = score[q=qrow+r][key=ln], pre-scaled

            float4v mx = s;
            #pragma unroll
            for (int off = 1; off < 16; off <<= 1)
                #pragma unroll
                for (int r = 0; r < 4; ++r)
                    mx[r] = fmaxf(mx[r], __shfl_xor(mx[r], off));
            float4v p;
            #pragma unroll
            for (int r = 0; r < 4; ++r) p[r] = __expf(s[r] - mx[r]);
            float4v sm = p;
            #pragma unroll
            for (int off = 1; off < 16; off <<= 1)
                #pragma unroll
                for (int r = 0; r < 4; ++r)
                    sm[r] += __shfl_xor(sm[r], off);
            #pragma unroll
            for (int r = 0; r < 4; ++r)
                Ls[B + 14848 + wave * 640 + (qrow + r) * 40 + ln] =
                    bf16rne(p[r] * __builtin_amdgcn_rcpf(sm[r]));

            short8 ap = *(const short8*)&Ls[B + 14848 + wave * 640 + ln * 40 + q8];
            #pragma unroll
            for (int dc = 0; dc < 4; ++dc) {
                short8 bv = *(const short8*)&Ls[B + 9216 + (dc * 16 + ln) * 88 + rb + q8];
                float4v o = (float4v){0.f, 0.f, 0.f, 0.f};
                o = mfma16(ap, bv, o);
                short4v t4;
                #pragma unroll
                for (int r = 0; r < 4; ++r) t4[r] = bf16rne(o[r]);
                pk[hp * 2 + j][dc] = t4;
            }
        }
    }

    // ---- phase 3: out = attn @ w_o^T, K-chunks = heads, w_o direct-frag ----
    for (int np = 0; np < 2; ++np) {
        size_t ooff[4];
        #pragma unroll
        for (int fc = 0; fc < 4; ++fc) {
            int n = np * 256 + wave * 64 + fc * 16 + ln;
            ooff[fc] = (size_t)n * HID;
        }
        float4v accO[4][4];
        #pragma unroll
        for (int fr = 0; fr < 4; ++fr)
            #pragma unroll
            for (int fc = 0; fc < 4; ++fc)
                accO[fr][fc] = (float4v){0.f, 0.f, 0.f, 0.f};

        #pragma unroll
        for (int hh = 0; hh < 8; ++hh) {
            __syncthreads();   // WAR on Lx
            #pragma unroll
            for (int dc = 0; dc < 4; ++dc) {
                short4v t4 = pk[hh][dc];
                #pragma unroll
                for (int r = 0; r < 4; ++r)
                    Lx[(rb + qrow + r) * 72 + dc * 16 + ln] = t4[r];
            }
            __syncthreads();
            #pragma unroll
            for (int ks = 0; ks < 2; ++ks) {
                const int ko = ks * 32 + q8;
                short8 a[4], b[4];
                #pragma unroll
                for (int fr = 0; fr < 4; ++fr)
                    a[fr] = *(const short8*)&Lx[(fr * 16 + ln) * 72 + ko];
                #pragma unroll
                for (int fc = 0; fc < 4; ++fc) {
                    if (tier >= 1) {
                        b[fc] = *(const short8*)&wob[ooff[fc] + hh * 64 + ko];
                    } else {
                        float4v f0 = *(const float4v*)&wof[ooff[fc] + hh * 64 + ko];
                        float4v f1 = *(const float4v*)&wof[ooff[fc] + hh * 64 + ko + 4];
                        b[fc] = pack8(f0, f1);
                    }
                }
                #pragma unroll
                for (int fr = 0; fr < 4; ++fr)
                    #pragma unroll
                    for (int fc = 0; fc < 4; ++fc)
                        accO[fr][fc] = mfma16(a[fr], b[fc], accO[fr][fc]);
            }
        }
        #pragma unroll
        for (int fr = 0; fr < 4; ++fr)
            #pragma unroll
            for (int fc = 0; fc < 4; ++fc)
                #pragma unroll
                for (int r = 0; r < 4; ++r)
                    out[(size_t)(m0 + fr * 16 + qrow + r) * HID +
                        np * 256 + wave * 64 + fc * 16 + ln] = accO[fr][fc][r];
    }
}

extern "C" void kernel_launch(void* const* d_in, const int* in_sizes, int n_in,
                              void* d_out, int out_size, void* d_ws, size_t ws_size,
                              hipStream_t stream) {
    const float* x    = (const float*)d_in[0];
    const float* wqkv = (const float*)d_in[1];
    const float* wo   = (const float*)d_in[2];
    float* out = (float*)d_out;

    const size_t n_x  = (size_t)65536 * HID;      // 33,554,432
    const size_t n_wq = (size_t)1536 * HID;       //    786,432
    const size_t n_wo = (size_t)HID * HID;        //    262,144
    const size_t need2 = (n_x + n_wq + n_wo) * 2; // ~66 MB
    const size_t need1 = (n_wq + n_wo) * 2;       //  2 MB

    int tier = 0;
    if (d_ws && ws_size >= need2) tier = 2;
    else if (d_ws && ws_size >= need1) tier = 1;

    short* xb  = nullptr;
    short* wqb = nullptr;
    short* wob = nullptr;
    if (tier == 2) {
        xb  = (short*)d_ws;
        wqb = xb + n_x;
        wob = wqb + n_wq;
        cvt_kernel<<<(int)(n_x / 1024), 256, 0, stream>>>(x, xb, (int)(n_x / 4));
        cvt_kernel<<<(int)(n_wq / 1024), 256, 0, stream>>>(wqkv, wqb, (int)(n_wq / 4));
        cvt_kernel<<<(int)(n_wo / 1024), 256, 0, stream>>>(wo, wob, (int)(n_wo / 4));
    } else if (tier == 1) {
        wqb = (short*)d_ws;
        wob = wqb + n_wq;
        cvt_kernel<<<(int)(n_wq / 1024), 256, 0, stream>>>(wqkv, wqb, (int)(n_wq / 4));
        cvt_kernel<<<(int)(n_wo / 1024), 256, 0, stream>>>(wo, wob, (int)(n_wo / 4));
    }

    fused_kernel<<<1024, 256, 0, stream>>>(x, xb, wqkv, wqb, wo, wob, tier, out);
}

// Round 3
// 465.224 us; speedup vs baseline: 1.6924x; 1.6924x over previous
//
#include <hip/hip_runtime.h>

// GameURMAttention: x[65536,512] -> QKV -> 8-head SDPA (S=16,D=64) -> out-proj.
// R3: per-head QKV+attention GEMM blocks (m97-style staging) + separate oproj GEMM.
//  tier A (ws>=137MB): xb + attnb + weights bf16 in ws
//  tier B (ws>= 70MB): attnb + weights bf16; x converted during staging
//  tier C (ws>=  2MB): weights bf16; attn fp32 via d_out + in-place oproj (R1 path)
//  tier D:             all conversions on the fly

#define HID 512

typedef __attribute__((ext_vector_type(4))) float  float4v;
typedef __attribute__((ext_vector_type(8))) short  short8;
typedef __attribute__((ext_vector_type(4))) short  short4v;
typedef __attribute__((ext_vector_type(8))) __bf16 bf16x8;

static __device__ __forceinline__ short bf16rne(float f) {
    union { float f; unsigned u; } v; v.f = f;
    unsigned u = v.u + 0x7FFFu + ((v.u >> 16) & 1u);
    return (short)(u >> 16);
}

static __device__ __forceinline__ short8 pack8(float4v a, float4v b) {
    short8 o;
    o[0] = bf16rne(a[0]); o[1] = bf16rne(a[1]); o[2] = bf16rne(a[2]); o[3] = bf16rne(a[3]);
    o[4] = bf16rne(b[0]); o[5] = bf16rne(b[1]); o[6] = bf16rne(b[2]); o[7] = bf16rne(b[3]);
    return o;
}

static __device__ __forceinline__ void cvt8_store(short* dst, const float* src) {
    float4v a = *(const float4v*)src;
    float4v b = *(const float4v*)(src + 4);
    *(short8*)dst = pack8(a, b);
}

static __device__ __forceinline__ float4v mfma16(short8 a, short8 b, float4v c) {
    union { short8 s; bf16x8 v; } ua, ub;
    ua.s = a; ub.s = b;
    return __builtin_amdgcn_mfma_f32_16x16x32_bf16(ua.v, ub.v, c, 0, 0, 0);
}

// ---------------- cvt: fp32 -> bf16 ----------------
__global__ void cvt_kernel(const float* __restrict__ src, short* __restrict__ dst, int n4) {
    int i = blockIdx.x * 256 + threadIdx.x;
    if (i >= n4) return;
    float4v v = *(const float4v*)(src + (size_t)i * 4);
    short4v o;
    o[0] = bf16rne(v[0]); o[1] = bf16rne(v[1]); o[2] = bf16rne(v[2]); o[3] = bf16rne(v[3]);
    *(short4v*)(dst + (size_t)i * 4) = o;
}

// ---------------- qkv + attention, one head per block ----------------
// grid 4096 = 512 m-tiles x 8 heads, 512 threads (8 waves).
// Tile M=128 (8 batches), N=192 (head h's Q|K|V cols), K=512, BK=64.
// Waves: wr=wave>>2 (M half), wc=wave&3 (48-col strip). 12 MFMA / wave / ks.
// XCD swizzle: 8 head-blocks of an m-tile land consecutively on one XCD.
__global__ __launch_bounds__(512, 4)
void qkv_head_kernel(const float* __restrict__ x, const short* __restrict__ xb, const int use_xb,
                     const float* __restrict__ wqf, const short* __restrict__ wqb, const int use_wb,
                     short* __restrict__ attnb, float* __restrict__ attnf, const int use_ab) {
    __shared__ __align__(16) union {
        struct { short a[128 * 72]; short b[192 * 72]; } st;                       // 46080 B
        struct { short q[128 * 72]; short k[128 * 72]; short vt[64 * 152]; short p[8 * 16 * 40]; } at; // 66560 B
    } L;

    const int tid  = threadIdx.x;
    const int wave = tid >> 6;
    const int lane = tid & 63;
    const int ln   = lane & 15;
    const int q8   = (lane >> 4) * 8;
    const int qrow = (lane >> 4) * 4;
    const int wr   = wave >> 2;
    const int wc   = wave & 3;

    const int g   = blockIdx.x;
    const int xcd = g & 7;
    const int j   = g >> 3;
    const int h   = j & 7;
    const int mt  = (j >> 3) * 8 + xcd;
    const int m0  = mt * 128;

    float4v acc[4][3];
    #pragma unroll
    for (int fr = 0; fr < 4; ++fr)
        #pragma unroll
        for (int fc = 0; fc < 3; ++fc)
            acc[fr][fc] = (float4v){0.f, 0.f, 0.f, 0.f};

    for (int kb = 0; kb < 8; ++kb) {
        __syncthreads();
        // stage A: X chunk 128x64 bf16, padded stride 72
        #pragma unroll
        for (int i = 0; i < 2; ++i) {
            int gg = tid + i * 512;
            int row = gg >> 3, c8 = (gg & 7) * 8;
            if (use_xb)
                *(short8*)&L.st.a[row * 72 + c8] =
                    *(const short8*)&xb[(size_t)(m0 + row) * HID + kb * 64 + c8];
            else
                cvt8_store(&L.st.a[row * 72 + c8], &x[(size_t)(m0 + row) * HID + kb * 64 + c8]);
        }
        // stage B: W rows for head h (Q|K|V gathered rows) 192x64
        #pragma unroll
        for (int i = 0; i < 3; ++i) {
            int gg = tid + i * 512;
            int n = gg >> 3, c8 = (gg & 7) * 8;
            int grow = (n >> 6) * HID + h * 64 + (n & 63);
            if (use_wb)
                *(short8*)&L.st.b[n * 72 + c8] =
                    *(const short8*)&wqb[(size_t)grow * HID + kb * 64 + c8];
            else
                cvt8_store(&L.st.b[n * 72 + c8], &wqf[(size_t)grow * HID + kb * 64 + c8]);
        }
        __syncthreads();
        #pragma unroll
        for (int ks = 0; ks < 2; ++ks) {
            const int ko = ks * 32 + q8;
            short8 a[4], b[3];
            #pragma unroll
            for (int fr = 0; fr < 4; ++fr)
                a[fr] = *(const short8*)&L.st.a[(wr * 64 + fr * 16 + ln) * 72 + ko];
            #pragma unroll
            for (int fc = 0; fc < 3; ++fc)
                b[fc] = *(const short8*)&L.st.b[(wc * 48 + fc * 16 + ln) * 72 + ko];
            #pragma unroll
            for (int fr = 0; fr < 4; ++fr)
                #pragma unroll
                for (int fc = 0; fc < 3; ++fc)
                    acc[fr][fc] = mfma16(a[fr], b[fc], acc[fr][fc]);
        }
    }
    __syncthreads();   // staging dead; union region becomes Q/K/VT/P

    // epilogue: C frags -> Q (x0.125) / K / V^T bf16 in LDS
    #pragma unroll
    for (int fr = 0; fr < 4; ++fr) {
        #pragma unroll
        for (int fc = 0; fc < 3; ++fc) {
            const int nb = wc * 48 + fc * 16;        // wave-uniform region selector
            const int n  = nb + ln;
            const int mb = wr * 64 + fr * 16 + qrow;
            const float4v v = acc[fr][fc];
            if (nb < 64) {
                #pragma unroll
                for (int r = 0; r < 4; ++r)
                    L.at.q[(mb + r) * 72 + n] = bf16rne(v[r] * 0.125f);
            } else if (nb < 128) {
                #pragma unroll
                for (int r = 0; r < 4; ++r)
                    L.at.k[(mb + r) * 72 + (n - 64)] = bf16rne(v[r]);
            } else {
                #pragma unroll
                for (int r = 0; r < 4; ++r)
                    L.at.vt[(n - 128) * 152 + mb + r] = bf16rne(v[r]);
            }
        }
    }
    // zero VT tail cols [128,152) and P key-pad [16,32)
    for (int i = tid; i < 64 * 24; i += 512)
        L.at.vt[(i / 24) * 152 + 128 + (i % 24)] = 0;
    for (int i = tid; i < 8 * 16 * 16; i += 512)
        L.at.p[(i >> 8) * 640 + ((i >> 4) & 15) * 40 + 16 + (i & 15)] = 0;
    __syncthreads();

    // attention: wave w = batch w (tile rows 16w..16w+15)
    {
        const int rb = wave * 16;
        const short* qp = &L.at.q[(rb + ln) * 72 + q8];
        const short* kp = &L.at.k[(rb + ln) * 72 + q8];
        short8 aq0 = *(const short8*)qp;
        short8 aq1 = *(const short8*)(qp + 32);
        short8 bk0 = *(const short8*)kp;
        short8 bk1 = *(const short8*)(kp + 32);
        float4v s = (float4v){0.f, 0.f, 0.f, 0.f};
        s = mfma16(aq0, bk0, s);
        s = mfma16(aq1, bk1, s);     // s[r] = score[q=qrow+r][key=ln], pre-scaled

        float4v mx = s;
        #pragma unroll
        for (int off = 1; off < 16; off <<= 1)
            #pragma unroll
            for (int r = 0; r < 4; ++r)
                mx[r] = fmaxf(mx[r], __shfl_xor(mx[r], off));
        float4v p;
        #pragma unroll
        for (int r = 0; r < 4; ++r) p[r] = __expf(s[r] - mx[r]);
        float4v sm = p;
        #pragma unroll
        for (int off = 1; off < 16; off <<= 1)
            #pragma unroll
            for (int r = 0; r < 4; ++r)
                sm[r] += __shfl_xor(sm[r], off);
        #pragma unroll
        for (int r = 0; r < 4; ++r)
            L.at.p[wave * 640 + (qrow + r) * 40 + ln] = bf16rne(p[r] * __builtin_amdgcn_rcpf(sm[r]));

        short8 ap = *(const short8*)&L.at.p[wave * 640 + ln * 40 + q8];
        #pragma unroll
        for (int dc = 0; dc < 4; ++dc) {
            short8 bv = *(const short8*)&L.at.vt[(dc * 16 + ln) * 152 + rb + q8];
            float4v o = (float4v){0.f, 0.f, 0.f, 0.f};
            o = mfma16(ap, bv, o);
            #pragma unroll
            for (int r = 0; r < 4; ++r) {
                const size_t oi = (size_t)(m0 + rb + qrow + r) * HID + h * 64 + dc * 16 + ln;
                if (use_ab) attnb[oi] = bf16rne(o[r]);
                else        attnf[oi] = o[r];
            }
        }
    }
}

// ---------------- oproj: out = attn(bf16) @ w_o^T, m97-style ----------------
// grid 2048 = 512 m-tiles x 4 n-tiles, 256 thr (4 waves, 2x2 wave grid, 64x64 each).
__global__ __launch_bounds__(256, 4)
void oproj_kernel(const short* __restrict__ attnb,
                  const float* __restrict__ wof, const short* __restrict__ wob,
                  const int use_wb, float* __restrict__ out) {
    __shared__ __align__(16) short A[128 * 72];
    __shared__ __align__(16) short B[128 * 72];

    const int tid  = threadIdx.x;
    const int wave = tid >> 6;
    const int lane = tid & 63;
    const int ln   = lane & 15;
    const int q8   = (lane >> 4) * 8;
    const int qrow = (lane >> 4) * 4;
    const int wr   = wave >> 1;
    const int wc   = wave & 1;

    const int g   = blockIdx.x;
    const int xcd = g & 7;
    const int j   = g >> 3;
    const int nt  = j & 3;
    const int mt  = (j >> 2) * 8 + xcd;
    const int m0  = mt * 128;
    const int n0  = nt * 128;

    float4v acc[4][4];
    #pragma unroll
    for (int fr = 0; fr < 4; ++fr)
        #pragma unroll
        for (int fc = 0; fc < 4; ++fc)
            acc[fr][fc] = (float4v){0.f, 0.f, 0.f, 0.f};

    for (int kb = 0; kb < 8; ++kb) {
        __syncthreads();
        #pragma unroll
        for (int i = 0; i < 4; ++i) {
            int gg = tid + i * 256;
            int row = gg >> 3, c8 = (gg & 7) * 8;
            *(short8*)&A[row * 72 + c8] =
                *(const short8*)&attnb[(size_t)(m0 + row) * HID + kb * 64 + c8];
            if (use_wb)
                *(short8*)&B[row * 72 + c8] =
                    *(const short8*)&wob[(size_t)(n0 + row) * HID + kb * 64 + c8];
            else
                cvt8_store(&B[row * 72 + c8], &wof[(size_t)(n0 + row) * HID + kb * 64 + c8]);
        }
        __syncthreads();
        #pragma unroll
        for (int ks = 0; ks < 2; ++ks) {
            const int ko = ks * 32 + q8;
            short8 a[4], b[4];
            #pragma unroll
            for (int fr = 0; fr < 4; ++fr)
                a[fr] = *(const short8*)&A[(wr * 64 + fr * 16 + ln) * 72 + ko];
            #pragma unroll
            for (int fc = 0; fc < 4; ++fc)
                b[fc] = *(const short8*)&B[(wc * 64 + fc * 16 + ln) * 72 + ko];
            #pragma unroll
            for (int fr = 0; fr < 4; ++fr)
                #pragma unroll
                for (int fc = 0; fc < 4; ++fc)
                    acc[fr][fc] = mfma16(a[fr], b[fc], acc[fr][fc]);
        }
    }
    #pragma unroll
    for (int fr = 0; fr < 4; ++fr)
        #pragma unroll
        for (int fc = 0; fc < 4; ++fc)
            #pragma unroll
            for (int r = 0; r < 4; ++r)
                out[(size_t)(m0 + wr * 64 + fr * 16 + qrow + r) * HID +
                    n0 + wc * 64 + fc * 16 + ln] = acc[fr][fc][r];
}

// ---------------- fallback oproj (tier C/D): in-place on d_out, R1-proven ----------------
__global__ __launch_bounds__(512, 2)
void oproj_inplace_kernel(float* __restrict__ io, const float* __restrict__ wof,
                          const short* __restrict__ wob, const int use_wb) {
    __shared__ __align__(16) short sA[64 * 40];
    __shared__ __align__(16) short sW2[512 * 40];

    const int tid  = threadIdx.x;
    const int wave = tid >> 6;
    const int lane = tid & 63;
    const int ln   = lane & 15;
    const int q8   = (lane >> 4) * 8;
    const int qrow = (lane >> 4) * 4;
    const int m0   = blockIdx.x * 64;

    float4v acc[4][4];
    #pragma unroll
    for (int fr = 0; fr < 4; ++fr)
        #pragma unroll
        for (int fc = 0; fc < 4; ++fc)
            acc[fr][fc] = (float4v){0.f, 0.f, 0.f, 0.f};

    for (int kb = 0; kb < 16; ++kb) {
        __syncthreads();
        if (tid < 256) {
            int row = tid >> 2, c8 = (tid & 3) * 8;
            cvt8_store(&sA[row * 40 + c8], &io[(size_t)(m0 + row) * HID + kb * 32 + c8]);
        }
        #pragma unroll
        for (int it = 0; it < 4; ++it) {
            int gg = tid + it * 512;
            int n = gg >> 2, c8 = (gg & 3) * 8;
            if (use_wb)
                *(short8*)&sW2[n * 40 + c8] = *(const short8*)&wob[(size_t)n * HID + kb * 32 + c8];
            else
                cvt8_store(&sW2[n * 40 + c8], &wof[(size_t)n * HID + kb * 32 + c8]);
        }
        __syncthreads();
        short8 a[4], b[4];
        #pragma unroll
        for (int fr = 0; fr < 4; ++fr)
            a[fr] = *(const short8*)&sA[(fr * 16 + ln) * 40 + q8];
        #pragma unroll
        for (int fc = 0; fc < 4; ++fc)
            b[fc] = *(const short8*)&sW2[(wave * 64 + fc * 16 + ln) * 40 + q8];
        #pragma unroll
        for (int fr = 0; fr < 4; ++fr)
            #pragma unroll
            for (int fc = 0; fc < 4; ++fc)
                acc[fr][fc] = mfma16(a[fr], b[fc], acc[fr][fc]);
    }
    #pragma unroll
    for (int fr = 0; fr < 4; ++fr)
        #pragma unroll
        for (int fc = 0; fc < 4; ++fc)
            #pragma unroll
            for (int r = 0; r < 4; ++r)
                io[(size_t)(m0 + fr * 16 + qrow + r) * HID + wave * 64 + fc * 16 + ln] =
                    acc[fr][fc][r];
}

extern "C" void kernel_launch(void* const* d_in, const int* in_sizes, int n_in,
                              void* d_out, int out_size, void* d_ws, size_t ws_size,
                              hipStream_t stream) {
    const float* x    = (const float*)d_in[0];
    const float* wqkv = (const float*)d_in[1];
    const float* wo   = (const float*)d_in[2];
    float* out = (float*)d_out;

    const size_t n_x  = (size_t)65536 * HID;   // 33,554,432
    const size_t n_wq = (size_t)1536 * HID;    //    786,432
    const size_t n_wo = (size_t)HID * HID;     //    262,144
    const size_t szA = (n_x * 2 + n_wq + n_wo) * 2;   // xb + attnb + weights
    const size_t szB = (n_x + n_wq + n_wo) * 2;       // attnb + weights
    const size_t szC = (n_wq + n_wo) * 2;             // weights only

    short* xb = nullptr; short* attnb = nullptr; short* wqb = nullptr; short* wob = nullptr;
    int use_xb = 0, use_ab = 0, use_wb = 0;
    short* ws = (short*)d_ws;

    if (d_ws && ws_size >= szA) {
        use_xb = use_ab = use_wb = 1;
        xb = ws; attnb = xb + n_x; wqb = attnb + n_x; wob = wqb + n_wq;
    } else if (d_ws && ws_size >= szB) {
        use_ab = use_wb = 1;
        attnb = ws; wqb = attnb + n_x; wob = wqb + n_wq;
    } else if (d_ws && ws_size >= szC) {
        use_wb = 1;
        wqb = ws; wob = wqb + n_wq;
    }

    if (use_xb)
        cvt_kernel<<<(int)(n_x / 1024), 256, 0, stream>>>(x, xb, (int)(n_x / 4));
    if (use_wb) {
        cvt_kernel<<<(int)(n_wq / 1024), 256, 0, stream>>>(wqkv, wqb, (int)(n_wq / 4));
        cvt_kernel<<<(int)(n_wo / 1024), 256, 0, stream>>>(wo, wob, (int)(n_wo / 4));
    }

    qkv_head_kernel<<<4096, 512, 0, stream>>>(x, xb, use_xb, wqkv, wqb, use_wb,
                                              attnb, out /*attnf*/, use_ab);

    if (use_ab)
        oproj_kernel<<<2048, 256, 0, stream>>>(attnb, wo, wob, use_wb, out);
    else
        oproj_inplace_kernel<<<1024, 512, 0, stream>>>(out, wo, wob, use_wb);
}